// Round 1
// baseline (4419.635 us; speedup 1.0000x reference)
//
#include <hip/hip_runtime.h>
#include <cstdint>
#include <cstddef>

#define DEV __device__ __forceinline__

DEV float lrelu(float x) { return x > 0.f ? x : 0.2f * x; }
DEV float eluf(float x)  { return x > 0.f ? x : expm1f(x); }

DEV float wave_sum(float v) {
  #pragma unroll
  for (int off = 32; off; off >>= 1) v += __shfl_xor(v, off, 64);
  return v;
}

// ---------------- CSR build (by dst) ----------------
__global__ void count_k(const int* __restrict__ dst, int* __restrict__ c, int E_) {
  int i = blockIdx.x * blockDim.x + threadIdx.x;
  if (i < E_) atomicAdd(&c[dst[i]], 1);
}

__global__ void scan_block_k(const int* __restrict__ in, int* __restrict__ out,
                             int* __restrict__ sums, int n) {
  __shared__ int tmp[1024];
  int tid = threadIdx.x;
  int i = blockIdx.x * 1024 + tid;
  int v = (i < n) ? in[i] : 0;
  tmp[tid] = v; __syncthreads();
  for (int off = 1; off < 1024; off <<= 1) {
    int t = (tid >= off) ? tmp[tid - off] : 0;
    __syncthreads();
    tmp[tid] += t;
    __syncthreads();
  }
  if (i < n) out[i] = tmp[tid] - v;   // exclusive
  if (sums && tid == 1023) sums[blockIdx.x] = tmp[1023];
}

__global__ void scan_finish_k(int* __restrict__ indptr, const int* __restrict__ sums_s,
                              int* __restrict__ cursor, int n, int total) {
  int i = blockIdx.x * blockDim.x + threadIdx.x;
  if (i >= n) return;
  int v = indptr[i] + sums_s[i >> 10];
  indptr[i] = v;
  cursor[i] = v;
  if (i == n - 1) indptr[n] = total;
}

__global__ void scatter_k(const int* __restrict__ src, const int* __restrict__ dst,
                          int* __restrict__ cursor, int* __restrict__ so, int E_) {
  int i = blockIdx.x * blockDim.x + threadIdx.x;
  if (i >= E_) return;
  int p = atomicAdd(&cursor[dst[i]], 1);
  so[p] = src[i];
}

// ---------------- GEMM: Y[n,128] = X[n,K] @ W[K,128], + attention-logit epilogue ----------------
template<int K>
__global__ __launch_bounds__(256) void gemm_al_k(
    const float* __restrict__ X, const float* __restrict__ W,
    float* __restrict__ Y, int accum, const float* __restrict__ bias,
    const float* __restrict__ a1, float* __restrict__ al1,
    const float* __restrict__ a2, float* __restrict__ al2,
    int heads, int n) {
  constexpr int K4 = K / 4;
  __shared__ float Wl[K * 128];
  __shared__ float4 Xl[32 * K4];
  const int tid = threadIdx.x;
  {
    const float4* W4 = (const float4*)W;
    float4* Wl4 = (float4*)Wl;
    for (int i = tid; i < K * 32; i += 256) Wl4[i] = W4[i];
  }
  const int r0 = blockIdx.x * 32;
  for (int i = tid; i < 32 * K4; i += 256) {
    int r = i / K4, cc = i - r * K4;
    int row = r0 + r;
    float4 v = make_float4(0.f, 0.f, 0.f, 0.f);
    if (row < n) v = ((const float4*)X)[(size_t)row * K4 + cc];
    Xl[i] = v;
  }
  __syncthreads();
  const int l = tid & 63, w = tid >> 6;
  float accA[8], accB[8];
  #pragma unroll
  for (int r = 0; r < 8; ++r) { accA[r] = 0.f; accB[r] = 0.f; }
  for (int k4 = 0; k4 < K4; ++k4) {
    const float* wp = &Wl[k4 * 4 * 128];
    float wa0 = wp[l],       wb0 = wp[64 + l];
    float wa1 = wp[128 + l], wb1 = wp[192 + l];
    float wa2 = wp[256 + l], wb2 = wp[320 + l];
    float wa3 = wp[384 + l], wb3 = wp[448 + l];
    #pragma unroll
    for (int r = 0; r < 8; ++r) {
      float4 xv = Xl[(w * 8 + r) * K4 + k4];
      accA[r] += xv.x * wa0 + xv.y * wa1 + xv.z * wa2 + xv.w * wa3;
      accB[r] += xv.x * wb0 + xv.y * wb1 + xv.z * wb2 + xv.w * wb3;
    }
  }
  #pragma unroll
  for (int r = 0; r < 8; ++r) {
    int row = r0 + w * 8 + r;
    if (row >= n) continue;
    float vA = accA[r], vB = accB[r];
    if (accum) { vA += Y[(size_t)row * 128 + l]; vB += Y[(size_t)row * 128 + 64 + l]; }
    if (bias)  { vA += bias[l]; vB += bias[64 + l]; }
    if (Y) {
      Y[(size_t)row * 128 + l]      = vA;
      Y[(size_t)row * 128 + 64 + l] = vB;
    }
    if (a1) {
      if (heads == 2) {
        float h0 = wave_sum(vA * a1[l]);
        float h1 = wave_sum(vB * a1[64 + l]);
        if (l == 0) { al1[row * 2] = h0; al1[row * 2 + 1] = h1; }
      } else {
        float h0 = wave_sum(vA * a1[l] + vB * a1[64 + l]);
        if (l == 0) al1[row] = h0;
      }
    }
    if (a2) {
      if (heads == 2) {
        float h0 = wave_sum(vA * a2[l]);
        float h1 = wave_sum(vB * a2[64 + l]);
        if (l == 0) { al2[row * 2] = h0; al2[row * 2 + 1] = h1; }
      } else {
        float h0 = wave_sum(vA * a2[l] + vB * a2[64 + l]);
        if (l == 0) al2[row] = h0;
      }
    }
  }
}

// ---------------- GAT gather: one wave per dst node, softmax over incoming edges ----------------
template<int HEADS, bool SELF, bool LNELU>
__global__ __launch_bounds__(256) void gat_gather_k(
    const int* __restrict__ indptr, const int* __restrict__ srcs,
    const float* __restrict__ xs, const float* __restrict__ als, const float* __restrict__ ald,
    const float* __restrict__ bias, const float* __restrict__ lng, const float* __restrict__ lnb,
    float* __restrict__ out, int n) {
  int node = (int)(((size_t)blockIdx.x * blockDim.x + threadIdx.x) >> 6);
  int l = threadIdx.x & 63;
  if (node >= n) return;
  int beg = indptr[node], end = indptr[node + 1];
  float ad0 = ald[node * HEADS];
  float ad1 = (HEADS == 2) ? ald[node * HEADS + 1] : 0.f;
  float m0 = -INFINITY, m1 = -INFINITY;
  if (SELF) {
    m0 = lrelu(als[node * HEADS] + ad0);
    if (HEADS == 2) m1 = lrelu(als[node * HEADS + 1] + ad1);
  }
  for (int e = beg; e < end; ++e) {
    int s = srcs[e];
    m0 = fmaxf(m0, lrelu(als[s * HEADS] + ad0));
    if (HEADS == 2) m1 = fmaxf(m1, lrelu(als[s * HEADS + 1] + ad1));
  }
  float s0 = 0.f, s1 = 0.f;
  float accx = 0.f, accy = 0.f;
  const bool hi = (HEADS == 2) && (l >= 32);  // lane l owns cols 2l,2l+1; head split at col 64
  const float2* x2 = (const float2*)xs;
  if (SELF) {
    float w0 = expf(lrelu(als[node * HEADS] + ad0) - m0);
    float w1 = (HEADS == 2) ? expf(lrelu(als[node * HEADS + 1] + ad1) - m1) : w0;
    s0 += w0; s1 += w1;
    float2 v = x2[(size_t)node * 64 + l];
    float wsel = hi ? w1 : w0;
    accx += wsel * v.x; accy += wsel * v.y;
  }
  for (int e = beg; e < end; ++e) {
    int s = srcs[e];
    float w0 = expf(lrelu(als[s * HEADS] + ad0) - m0);
    float w1 = (HEADS == 2) ? expf(lrelu(als[s * HEADS + 1] + ad1) - m1) : w0;
    s0 += w0; s1 += w1;
    float2 v = x2[(size_t)s * 64 + l];
    float wsel = hi ? w1 : w0;
    accx += wsel * v.x; accy += wsel * v.y;
  }
  float denom = (hi ? s1 : s0) + 1e-16f;
  float ox = accx / denom + bias[2 * l];
  float oy = accy / denom + bias[2 * l + 1];
  if (LNELU) {
    float sum = wave_sum(ox + oy);
    float sq  = wave_sum(ox * ox + oy * oy);
    float mu  = sum * (1.f / 128.f);
    float var = sq * (1.f / 128.f) - mu * mu;
    float inv = rsqrtf(var + 1e-5f);
    ox = (ox - mu) * inv * lng[2 * l]     + lnb[2 * l];
    oy = (oy - mu) * inv * lng[2 * l + 1] + lnb[2 * l + 1];
    ox = eluf(ox); oy = eluf(oy);
  }
  ((float2*)out)[(size_t)node * 64 + l] = make_float2(ox, oy);
}

// ---------------- plain neighbor sum (GraphConv agg for SAG) ----------------
__global__ __launch_bounds__(256) void neigh_gather_k(
    const int* __restrict__ indptr, const int* __restrict__ srcs,
    const float* __restrict__ x, float* __restrict__ out, int n) {
  int node = (int)(((size_t)blockIdx.x * blockDim.x + threadIdx.x) >> 6);
  int l = threadIdx.x & 63;
  if (node >= n) return;
  int beg = indptr[node], end = indptr[node + 1];
  float2 acc = make_float2(0.f, 0.f);
  const float2* x2 = (const float2*)x;
  for (int e = beg; e < end; ++e) {
    int s = srcs[e];
    float2 v = x2[(size_t)s * 64 + l];
    acc.x += v.x; acc.y += v.y;
  }
  ((float2*)out)[(size_t)node * 64 + l] = acc;
}

// ---------------- SAG attention score ----------------
__global__ __launch_bounds__(256) void sag_attn_k(
    const float* __restrict__ x, const float* __restrict__ neigh,
    const float* __restrict__ w_rel, const float* __restrict__ b_rel,
    const float* __restrict__ w_root, float* __restrict__ attn, int n) {
  int node = (int)(((size_t)blockIdx.x * blockDim.x + threadIdx.x) >> 6);
  int l = threadIdx.x & 63;
  if (node >= n) return;
  float2 nv = ((const float2*)neigh)[(size_t)node * 64 + l];
  float2 xv = ((const float2*)x)[(size_t)node * 64 + l];
  float2 wr = ((const float2*)w_rel)[l];
  float2 wo = ((const float2*)w_root)[l];
  float v = nv.x * wr.x + nv.y * wr.y + xv.x * wo.x + xv.y * wo.y;
  v = wave_sum(v);
  if (l == 0) attn[node] = v + b_rel[0];
}

// ---------------- SAG per-batch softmax + weighted pool (batch array is sorted) ----------------
__global__ __launch_bounds__(256) void sag_emb_k(
    const float* __restrict__ x, const float* __restrict__ attn,
    const int* __restrict__ batch, float* __restrict__ emb, int n, int nb) {
  int b = (int)(((size_t)blockIdx.x * blockDim.x + threadIdx.x) >> 6);
  int l = threadIdx.x & 63;
  if (b >= nb) return;
  int lo = 0, hiq = n;
  while (lo < hiq) { int mid = (lo + hiq) >> 1; if (batch[mid] < b) lo = mid + 1; else hiq = mid; }
  int beg = lo;
  hiq = n;
  while (lo < hiq) { int mid = (lo + hiq) >> 1; if (batch[mid] < b + 1) lo = mid + 1; else hiq = mid; }
  int end = lo;
  float m = -INFINITY;
  for (int i = beg; i < end; ++i) m = fmaxf(m, attn[i]);
  float s = 0.f;
  float2 acc = make_float2(0.f, 0.f);
  const float2* x2 = (const float2*)x;
  for (int i = beg; i < end; ++i) {
    float w = expf(attn[i] - m);
    s += w;
    float2 v = x2[(size_t)i * 64 + l];
    acc.x += w * v.x; acc.y += w * v.y;
  }
  float inv = 1.f / (s + 1e-16f);
  ((float2*)emb)[(size_t)b * 64 + l] = make_float2(acc.x * inv, acc.y * inv);
}

extern "C" void kernel_launch(void* const* d_in, const int* in_sizes, int n_in,
                              void* d_out, int out_size, void* d_ws, size_t ws_size,
                              hipStream_t stream) {
  (void)n_in; (void)ws_size;
  const float* h_x         = (const float*)d_in[0];
  const float* t_x         = (const float*)d_in[1];
  const float* W_gat       = (const float*)d_in[2];
  const float* a_src_gat   = (const float*)d_in[3];
  const float* a_dst_gat   = (const float*)d_in[4];
  const float* b_gat       = (const float*)d_in[5];
  const float* ln_g        = (const float*)d_in[6];
  const float* ln_b        = (const float*)d_in[7];
  const float* W_intra     = (const float*)d_in[8];
  const float* a_src_intra = (const float*)d_in[9];
  const float* a_dst_intra = (const float*)d_in[10];
  const float* b_intra     = (const float*)d_in[11];
  const float* W_inter_src = (const float*)d_in[12];
  const float* W_inter_dst = (const float*)d_in[13];
  const float* a_src_inter = (const float*)d_in[14];
  const float* a_dst_inter = (const float*)d_in[15];
  const float* b_inter     = (const float*)d_in[16];
  const float* W_reduce    = (const float*)d_in[17];
  const float* b_reduce    = (const float*)d_in[18];
  const float* w_rel       = (const float*)d_in[19];
  const float* b_rel       = (const float*)d_in[20];
  const float* w_root      = (const float*)d_in[21];
  const int* h_ei          = (const int*)d_in[22];
  const int* t_ei          = (const int*)d_in[23];
  const int* b_ei          = (const int*)d_in[24];
  const int* h_batch       = (const int*)d_in[25];
  const int* t_batch       = (const int*)d_in[26];

  const int N = in_sizes[0] / 64;
  const int E = in_sizes[22] / 2;
  const size_t ND = (size_t)N * 128;
  const int Bn = (int)(((size_t)out_size - 6 * ND) / 256);

  float* out  = (float*)d_out;
  float* o_hf = out;                       // h_fused (stages h_e until fuse GEMM)
  float* o_tf = out + ND;                  // t_fused (stages t_e)
  float* o_he = out + 2 * ND;              // h_emb [B,128]
  float* o_te = o_he + (size_t)Bn * 128;   // t_emb
  float* o_hi = o_te + (size_t)Bn * 128;   // h_intra
  float* o_ti = o_hi + ND;                 // t_intra
  float* o_hn = o_ti + ND;                 // h_inter
  float* o_tn = o_hn + ND;                 // t_inter

  float* bufA = (float*)d_ws;              // [N,128] transformed src features
  float* als  = bufA + ND;                 // [N*2]
  float* ald  = als + (size_t)N * 2;       // [N*2]
  int* iw = (int*)(ald + (size_t)N * 2);
  const int IPAD = ((N + 1 + 3) / 4) * 4;
  const size_t CS = (size_t)IPAD + (size_t)N + (size_t)E;
  int* ip_h  = iw;           int* c_h  = ip_h  + IPAD; int* s_h  = c_h  + N;
  int* ip_t  = iw + CS;      int* c_t  = ip_t  + IPAD; int* s_t  = c_t  + N;
  int* ip_bf = iw + 2 * CS;  int* c_bf = ip_bf + IPAD; int* s_bf = c_bf + N;
  int* ip_br = iw + 3 * CS;  int* c_br = ip_br + IPAD; int* s_br = c_br + N;
  int* sums   = iw + 4 * CS;
  int* sums_s = sums + 256;

  const int gE    = (E + 255) / 256;
  const int gN256 = (N + 255) / 256;
  const int nblk  = (N + 1023) / 1024;
  const int gG    = (N + 31) / 32;
  const int gW    = (N + 3) / 4;
  const int gB    = (Bn + 3) / 4;

  auto build_csr = [&](const int* srcp, const int* dstp, int* indptr, int* c, int* so) {
    hipMemsetAsync(c, 0, (size_t)N * sizeof(int), stream);
    count_k<<<gE, 256, 0, stream>>>(dstp, c, E);
    scan_block_k<<<nblk, 1024, 0, stream>>>(c, indptr, sums, N);
    scan_block_k<<<1, 1024, 0, stream>>>(sums, sums_s, nullptr, nblk);
    scan_finish_k<<<gN256, 256, 0, stream>>>(indptr, sums_s, c, N, E);
    scatter_k<<<gE, 256, 0, stream>>>(srcp, dstp, c, so, E);
  };

  build_csr(h_ei,     h_ei + E, ip_h,  c_h,  s_h);
  build_csr(t_ei,     t_ei + E, ip_t,  c_t,  s_t);
  build_csr(b_ei,     b_ei + E, ip_bf, c_bf, s_bf);  // dst = b row1 (t side)
  build_csr(b_ei + E, b_ei,     ip_br, c_br, s_br);  // dst = b row0 (h side)

  // ---- feature_conv GAT (H=2) + LN + ELU -> h_e / t_e staged in fused slots ----
  gemm_al_k<64><<<gG, 256, 0, stream>>>(h_x, W_gat, bufA, 0, nullptr,
                                        a_src_gat, als, a_dst_gat, ald, 2, N);
  gat_gather_k<2, true, true><<<gW, 256, 0, stream>>>(ip_h, s_h, bufA, als, ald,
                                                      b_gat, ln_g, ln_b, o_hf, N);
  gemm_al_k<64><<<gG, 256, 0, stream>>>(t_x, W_gat, bufA, 0, nullptr,
                                        a_src_gat, als, a_dst_gat, ald, 2, N);
  gat_gather_k<2, true, true><<<gW, 256, 0, stream>>>(ip_t, s_t, bufA, als, ald,
                                                      b_gat, ln_g, ln_b, o_tf, N);

  // ---- intra GAT (H=1, self loops) ----
  gemm_al_k<128><<<gG, 256, 0, stream>>>(o_hf, W_intra, bufA, 0, nullptr,
                                         a_src_intra, als, a_dst_intra, ald, 1, N);
  gat_gather_k<1, true, false><<<gW, 256, 0, stream>>>(ip_h, s_h, bufA, als, ald,
                                                       b_intra, nullptr, nullptr, o_hi, N);
  gemm_al_k<128><<<gG, 256, 0, stream>>>(o_tf, W_intra, bufA, 0, nullptr,
                                         a_src_intra, als, a_dst_intra, ald, 1, N);
  gat_gather_k<1, true, false><<<gW, 256, 0, stream>>>(ip_t, s_t, bufA, als, ald,
                                                       b_intra, nullptr, nullptr, o_ti, N);

  // ---- inter GAT: t_inter (src=h_e, dst=t side) ----
  gemm_al_k<128><<<gG, 256, 0, stream>>>(o_hf, W_inter_src, bufA, 0, nullptr,
                                         a_src_inter, als, nullptr, nullptr, 1, N);
  gemm_al_k<128><<<gG, 256, 0, stream>>>(o_tf, W_inter_dst, nullptr, 0, nullptr,
                                         a_dst_inter, ald, nullptr, nullptr, 1, N);
  gat_gather_k<1, false, false><<<gW, 256, 0, stream>>>(ip_bf, s_bf, bufA, als, ald,
                                                        b_inter, nullptr, nullptr, o_tn, N);

  // ---- inter GAT: h_inter (src=t_e, dst=h side) ----
  gemm_al_k<128><<<gG, 256, 0, stream>>>(o_tf, W_inter_src, bufA, 0, nullptr,
                                         a_src_inter, als, nullptr, nullptr, 1, N);
  gemm_al_k<128><<<gG, 256, 0, stream>>>(o_hf, W_inter_dst, nullptr, 0, nullptr,
                                         a_dst_inter, ald, nullptr, nullptr, 1, N);
  gat_gather_k<1, false, false><<<gW, 256, 0, stream>>>(ip_br, s_br, bufA, als, ald,
                                                        b_inter, nullptr, nullptr, o_hn, N);

  // ---- fuse: [intra | inter] @ W_reduce + b_reduce (overwrites h_e / t_e) ----
  gemm_al_k<128><<<gG, 256, 0, stream>>>(o_hi, W_reduce, o_hf, 0, nullptr,
                                         nullptr, nullptr, nullptr, nullptr, 1, N);
  gemm_al_k<128><<<gG, 256, 0, stream>>>(o_hn, W_reduce + 128 * 128, o_hf, 1, b_reduce,
                                         nullptr, nullptr, nullptr, nullptr, 1, N);
  gemm_al_k<128><<<gG, 256, 0, stream>>>(o_ti, W_reduce, o_tf, 0, nullptr,
                                         nullptr, nullptr, nullptr, nullptr, 1, N);
  gemm_al_k<128><<<gG, 256, 0, stream>>>(o_tn, W_reduce + 128 * 128, o_tf, 1, b_reduce,
                                         nullptr, nullptr, nullptr, nullptr, 1, N);

  // ---- SAG readout h ----
  neigh_gather_k<<<gW, 256, 0, stream>>>(ip_h, s_h, o_hf, bufA, N);
  sag_attn_k<<<gW, 256, 0, stream>>>(o_hf, bufA, w_rel, b_rel, w_root, als, N);
  sag_emb_k<<<gB, 256, 0, stream>>>(o_hf, als, h_batch, o_he, N, Bn);

  // ---- SAG readout t ----
  neigh_gather_k<<<gW, 256, 0, stream>>>(ip_t, s_t, o_tf, bufA, N);
  sag_attn_k<<<gW, 256, 0, stream>>>(o_tf, bufA, w_rel, b_rel, w_root, als, N);
  sag_emb_k<<<gB, 256, 0, stream>>>(o_tf, als, t_batch, o_te, N, Bn);
}